// Round 1
// baseline (286.942 us; speedup 1.0000x reference)
//
#include <hip/hip_runtime.h>
#include <cstddef>

#define D_MODEL   256
#define N_HEADS   8
#define N_LEVELS  4
#define N_POINTS  4
#define D_HEAD    32
#define HLP       128      // N_HEADS*N_LEVELS*N_POINTS
#define NBATCH    4
#define LQ        4096
#define S_LEN     7680     // 4096+2048+1024+512

// ---------------------------------------------------------------------------
// Generic fp32 GEMM with bias: C[M,N] = A[M,K] @ B[K,N] + bias[N]
// 64x64 tile, 256 threads, 4x4 microtile, K-tile 16. M,N %64==0, K%16==0.
// ---------------------------------------------------------------------------
__global__ __launch_bounds__(256) void gemm_bias_kernel(
    const float* __restrict__ A, const float* __restrict__ B,
    const float* __restrict__ bias, float* __restrict__ C,
    int M, int N, int K)
{
    // pad row stride to 68 floats (272 B): keeps float4 LDS stores 16B-aligned,
    // bank stride 4 -> worst 2-way conflict (free on gfx950).
    __shared__ float As[16][68];
    __shared__ float Bs[16][68];

    const int tid  = threadIdx.x;
    const int tx   = tid & 15;        // 0..15 -> N direction
    const int ty   = tid >> 4;        // 0..15 -> M direction
    const int col0 = blockIdx.x * 64;
    const int row0 = blockIdx.y * 64;

    float acc[4][4] = {};

    for (int k0 = 0; k0 < K; k0 += 16) {
        // --- stage A tile (64 rows x 16 k), transposed into As[k][row] ---
        {
            const int r = tid >> 2;            // 0..63
            const int q = (tid & 3) * 4;       // 0,4,8,12
            const float4 av = *(const float4*)(A + (size_t)(row0 + r) * K + k0 + q);
            As[q + 0][r] = av.x;
            As[q + 1][r] = av.y;
            As[q + 2][r] = av.z;
            As[q + 3][r] = av.w;
        }
        // --- stage B tile (16 k x 64 cols) ---
        {
            const int rb = tid >> 4;           // 0..15
            const int cb = (tid & 15) * 4;     // 0..60
            const float4 bv = *(const float4*)(B + (size_t)(k0 + rb) * N + col0 + cb);
            *(float4*)&Bs[rb][cb] = bv;
        }
        __syncthreads();

        #pragma unroll
        for (int kk = 0; kk < 16; ++kk) {
            float a0 = As[kk][ty * 4 + 0];
            float a1 = As[kk][ty * 4 + 1];
            float a2 = As[kk][ty * 4 + 2];
            float a3 = As[kk][ty * 4 + 3];
            float b0 = Bs[kk][tx * 4 + 0];
            float b1 = Bs[kk][tx * 4 + 1];
            float b2 = Bs[kk][tx * 4 + 2];
            float b3 = Bs[kk][tx * 4 + 3];
            acc[0][0] += a0 * b0; acc[0][1] += a0 * b1; acc[0][2] += a0 * b2; acc[0][3] += a0 * b3;
            acc[1][0] += a1 * b0; acc[1][1] += a1 * b1; acc[1][2] += a1 * b2; acc[1][3] += a1 * b3;
            acc[2][0] += a2 * b0; acc[2][1] += a2 * b1; acc[2][2] += a2 * b2; acc[2][3] += a2 * b3;
            acc[3][0] += a3 * b0; acc[3][1] += a3 * b1; acc[3][2] += a3 * b2; acc[3][3] += a3 * b3;
        }
        __syncthreads();
    }

    #pragma unroll
    for (int i = 0; i < 4; ++i) {
        const int r = row0 + ty * 4 + i;
        float4 o;
        const int c = col0 + tx * 4;
        o.x = acc[i][0] + bias[c + 0];
        o.y = acc[i][1] + bias[c + 1];
        o.z = acc[i][2] + bias[c + 2];
        o.w = acc[i][3] + bias[c + 3];
        *(float4*)(C + (size_t)r * N + c) = o;
    }
}

// ---------------------------------------------------------------------------
// Sampling + softmax. One block per (n,q). 256 threads = 8 heads x 32 dims.
// Phase 1 (128 threads): location calc for the 128 (m,l,p) points -> LDS.
// Phase 2: per-head softmax over 16 logits.
// Phase 3 (256 threads): accumulate 16 points x 32 dims with linear interp.
// ---------------------------------------------------------------------------
__global__ __launch_bounds__(256) void sample_kernel(
    const float* __restrict__ Poff, const float* __restrict__ Paw,
    const float* __restrict__ refp, const int* __restrict__ shapes,
    const int* __restrict__ lstart, const float* __restrict__ value,
    float* __restrict__ tout)
{
    __shared__ int   sg0[HLP];
    __shared__ int   sg1[HLP];
    __shared__ float sw[HLP];
    __shared__ float se[HLP];
    __shared__ float smax[N_HEADS];
    __shared__ float srsum[N_HEADS];

    const int nq  = blockIdx.x;           // n*LQ + q
    const int n   = nq >> 12;             // LQ = 4096
    const int tid = threadIdx.x;

    if (tid < HLP) {
        const int l = (tid >> 2) & 3;     // tid = m*16 + l*4 + p
        const float logit = Paw[(size_t)nq * HLP + tid];
        const float off   = Poff[(size_t)nq * HLP + tid];
        const float T     = (float)shapes[l];
        const float ref   = refp[(size_t)nq * N_LEVELS + l];
        float x = ref * T + off - 0.5f;           // loc*T - 0.5
        x = fminf(fmaxf(x, 0.0f), T - 1.0f);
        const float x0 = floorf(x);
        const int   i0 = (int)x0;
        const int   i1 = min(i0 + 1, shapes[l] - 1);
        const int   base = lstart[l];
        sg0[tid] = i0 + base;
        sg1[tid] = i1 + base;
        sw[tid]  = x - x0;
        se[tid]  = logit;
    }
    __syncthreads();
    if (tid < N_HEADS) {
        float mx = -1e30f;
        #pragma unroll
        for (int i = 0; i < 16; ++i) mx = fmaxf(mx, se[tid * 16 + i]);
        smax[tid] = mx;
    }
    __syncthreads();
    if (tid < HLP) {
        se[tid] = __expf(se[tid] - smax[tid >> 4]);
    }
    __syncthreads();
    if (tid < N_HEADS) {
        float s = 0.f;
        #pragma unroll
        for (int i = 0; i < 16; ++i) s += se[tid * 16 + i];
        srsum[tid] = 1.0f / s;
    }
    __syncthreads();

    const int m = tid >> 5;               // head
    const int d = tid & 31;               // dim
    const float rs = srsum[m];
    // value[((n*S + s)*8 + m)*32 + d] = vbase + s*256
    const float* vbase = value + (size_t)n * S_LEN * 256 + m * 32 + d;

    float acc = 0.f;
    #pragma unroll
    for (int i = 0; i < 16; ++i) {
        const int j = m * 16 + i;
        const float a = se[j] * rs;
        const float w = sw[j];
        const float v0 = vbase[(size_t)sg0[j] * 256];
        const float v1 = vbase[(size_t)sg1[j] * 256];
        acc += a * (v0 + w * (v1 - v0));
    }
    tout[(size_t)nq * 256 + tid] = acc;
}

// ---------------------------------------------------------------------------
extern "C" void kernel_launch(void* const* d_in, const int* in_sizes, int n_in,
                              void* d_out, int out_size, void* d_ws, size_t ws_size,
                              hipStream_t stream)
{
    const float* query  = (const float*)d_in[0];
    const float* refp   = (const float*)d_in[1];
    const float* inflat = (const float*)d_in[2];
    const int*   shapes = (const int*)d_in[3];
    const int*   lstart = (const int*)d_in[4];
    const float* W_off  = (const float*)d_in[5];
    const float* b_off  = (const float*)d_in[6];
    const float* W_aw   = (const float*)d_in[7];
    const float* b_aw   = (const float*)d_in[8];
    const float* W_v    = (const float*)d_in[9];
    const float* b_v    = (const float*)d_in[10];
    const float* W_out  = (const float*)d_in[11];
    const float* b_out  = (const float*)d_in[12];

    const int M_val  = NBATCH * S_LEN;   // 30720
    const int M_q    = NBATCH * LQ;      // 16384

    // workspace layout (floats)
    float* value = (float*)d_ws;                          // 30720*256
    float* Poff  = value + (size_t)M_val * D_MODEL;       // 16384*128
    float* Paw   = Poff + (size_t)M_q * HLP;              // 16384*128
    float* tbuf  = Paw + (size_t)M_q * HLP;               // 16384*256

    // 1. value = input_flatten @ W_v + b_v
    gemm_bias_kernel<<<dim3(D_MODEL / 64, M_val / 64), 256, 0, stream>>>(
        inflat, W_v, b_v, value, M_val, D_MODEL, D_MODEL);
    // 2. Poff = query @ W_off + b_off
    gemm_bias_kernel<<<dim3(HLP / 64, M_q / 64), 256, 0, stream>>>(
        query, W_off, b_off, Poff, M_q, HLP, D_MODEL);
    // 3. Paw = query @ W_aw + b_aw
    gemm_bias_kernel<<<dim3(HLP / 64, M_q / 64), 256, 0, stream>>>(
        query, W_aw, b_aw, Paw, M_q, HLP, D_MODEL);
    // 4. sampling + softmax -> tbuf
    sample_kernel<<<M_q, 256, 0, stream>>>(
        Poff, Paw, refp, shapes, lstart, value, tbuf);
    // 5. out = tbuf @ W_out + b_out
    gemm_bias_kernel<<<dim3(D_MODEL / 64, M_q / 64), 256, 0, stream>>>(
        tbuf, W_out, b_out, (float*)d_out, M_q, D_MODEL, D_MODEL);
}

// Round 2
// 180.075 us; speedup vs baseline: 1.5935x; 1.5935x over previous
//
#include <hip/hip_runtime.h>
#include <hip/hip_bf16.h>
#include <cstddef>
#include <cstdint>

#define D_MODEL   256
#define N_HEADS   8
#define N_LEVELS  4
#define N_POINTS  4
#define D_HEAD    32
#define HLP       128      // N_HEADS*N_LEVELS*N_POINTS
#define NBATCH    4
#define LQ        4096
#define S_LEN     7680     // 4096+2048+1024+512

typedef __attribute__((ext_vector_type(8))) short  short8;
typedef __attribute__((ext_vector_type(4))) float  f32x4;
typedef __attribute__((ext_vector_type(8))) unsigned short ushort8;

__device__ __forceinline__ unsigned short f2bf(float x) {
    __hip_bfloat16 h = __float2bfloat16(x);
    return *reinterpret_cast<unsigned short*>(&h);
}
__device__ __forceinline__ float bf2f(unsigned short u) {
    unsigned int v = ((unsigned int)u) << 16;
    return *reinterpret_cast<float*>(&v);
}

__device__ __forceinline__ void gload_lds16(const void* g, void* l) {
    __builtin_amdgcn_global_load_lds(
        (const __attribute__((address_space(1))) void*)g,
        (__attribute__((address_space(3))) void*)l,
        16, 0, 0);
}

// ---------------------------------------------------------------------------
// fp32 -> bf16 elementwise conversion (n % 8 == 0)
// ---------------------------------------------------------------------------
__global__ __launch_bounds__(256) void conv_bf16_kernel(
    const float* __restrict__ src, unsigned short* __restrict__ dst, int n)
{
    size_t i = ((size_t)blockIdx.x * blockDim.x + threadIdx.x) * 8;
    if (i >= (size_t)n) return;
    float4 a = *(const float4*)(src + i);
    float4 b = *(const float4*)(src + i + 4);
    ushort8 r;
    r[0] = f2bf(a.x); r[1] = f2bf(a.y); r[2] = f2bf(a.z); r[3] = f2bf(a.w);
    r[4] = f2bf(b.x); r[5] = f2bf(b.y); r[6] = f2bf(b.z); r[7] = f2bf(b.w);
    *(ushort8*)(dst + i) = r;
}

// ---------------------------------------------------------------------------
// Transpose weight [K=256][N] fp32 -> [N][K=256] bf16. grid (N/64, 4).
// ---------------------------------------------------------------------------
__global__ __launch_bounds__(256) void transpose_w_kernel(
    const float* __restrict__ src, unsigned short* __restrict__ dst, int N)
{
    __shared__ float t[64][65];
    const int k0 = blockIdx.y * 64, n0 = blockIdx.x * 64;
    const int tid = threadIdx.x;
    #pragma unroll
    for (int i = 0; i < 16; ++i) {
        int idx = tid + i * 256;
        int kk = idx >> 6, nn = idx & 63;
        t[kk][nn] = src[(size_t)(k0 + kk) * N + n0 + nn];
    }
    __syncthreads();
    #pragma unroll
    for (int i = 0; i < 16; ++i) {
        int idx = tid + i * 256;
        int nn = idx >> 6, kk = idx & 63;
        dst[(size_t)(n0 + nn) * 256 + k0 + kk] = f2bf(t[kk][nn]);
    }
}

__global__ void bias_cat_kernel(const float* __restrict__ b0,
                                const float* __restrict__ b1,
                                float* __restrict__ out)
{
    int t = threadIdx.x;
    out[t] = (t < 128) ? b0[t] : b1[t - 128];
}

// ---------------------------------------------------------------------------
// bf16 MFMA GEMM: C[M,256] = A[M,256] @ Bt[256,256]^T + bias.
// A row-major bf16 [M][256]; Bt is N-major bf16 [256 n][256 k].
// 128x128 tile, 256 threads = 4 waves (2x2), 16x16x32 MFMA, BK=32.
// LDS in fragment order, staged via global_load_lds width 16.
// ---------------------------------------------------------------------------
template <bool BF16_OUT>
__global__ __launch_bounds__(256) void mfma_gemm_kernel(
    const unsigned short* __restrict__ A,
    const unsigned short* __restrict__ Bt,
    const float* __restrict__ bias,
    void* __restrict__ Cout, int M)
{
    __shared__ unsigned short Als[8][64][8];   // 8 KiB: [im][lane][8 bf16]
    __shared__ unsigned short Bls[8][64][8];   // 8 KiB: [in][lane][8 bf16]

    const int tid  = threadIdx.x;
    const int lane = tid & 63;
    const int w    = tid >> 6;        // wave 0..3
    const int wm   = w & 1;           // row half
    const int wn   = w >> 1;          // col half
    const int row0 = blockIdx.y * 128;
    const int col0 = blockIdx.x * 128;

    const int lr = (lane & 15);       // fragment row (A) / n (B)
    const int lk = (lane >> 4) * 8;   // fragment k offset

    f32x4 acc[4][4] = {};

    for (int kt = 0; kt < 8; ++kt) {
        const int k0 = kt * 32;
        // stage A chunks im = 2w, 2w+1 ; B chunks in = 2w, 2w+1
        #pragma unroll
        for (int c = 0; c < 2; ++c) {
            const int im = w * 2 + c;
            const size_t ga = (size_t)(row0 + im * 16 + lr) * 256 + k0 + lk;
            gload_lds16(A + ga, &Als[im][0][0]);
            const int in = w * 2 + c;
            const size_t gb = (size_t)(col0 + in * 16 + lr) * 256 + k0 + lk;
            gload_lds16(Bt + gb, &Bls[in][0][0]);
        }
        __syncthreads();

        short8 af[4], bfr[4];
        #pragma unroll
        for (int i = 0; i < 4; ++i) af[i]  = *(const short8*)&Als[wm * 4 + i][lane][0];
        #pragma unroll
        for (int j = 0; j < 4; ++j) bfr[j] = *(const short8*)&Bls[wn * 4 + j][lane][0];

        #pragma unroll
        for (int i = 0; i < 4; ++i)
            #pragma unroll
            for (int j = 0; j < 4; ++j)
                acc[i][j] = __builtin_amdgcn_mfma_f32_16x16x32_bf16(
                    af[i], bfr[j], acc[i][j], 0, 0, 0);
        __syncthreads();
    }

    // epilogue: C/D layout col=lane&15, row=(lane>>4)*4+reg
    const int r0 = row0 + wm * 64;
    const int c0 = col0 + wn * 64;
    const int prow = (lane >> 4) * 4;
    const int pcol = lane & 15;
    #pragma unroll
    for (int j = 0; j < 4; ++j) {
        const int col = c0 + j * 16 + pcol;
        const float bs = bias[col];
        #pragma unroll
        for (int i = 0; i < 4; ++i) {
            #pragma unroll
            for (int r = 0; r < 4; ++r) {
                const int row = r0 + i * 16 + prow + r;
                const float v = acc[i][j][r] + bs;
                if (BF16_OUT)
                    ((unsigned short*)Cout)[(size_t)row * 256 + col] = f2bf(v);
                else
                    ((float*)Cout)[(size_t)row * 256 + col] = v;
            }
        }
    }
}

// ---------------------------------------------------------------------------
// Sampling + softmax. One block per (n,q). 128 threads = 8 heads x 16 dimpairs.
// P: [nq][256] fp32 (cols 0..127 = offset logits, 128..255 = aw logits).
// value: bf16 [n][s][head][32]. tout: bf16 [nq][256].
// ---------------------------------------------------------------------------
__global__ __launch_bounds__(128) void sample_kernel(
    const float* __restrict__ P, const float* __restrict__ refp,
    const int* __restrict__ shapes, const int* __restrict__ lstart,
    const unsigned short* __restrict__ value, unsigned short* __restrict__ tout)
{
    __shared__ int   sg0[HLP];
    __shared__ int   sg1[HLP];
    __shared__ float sw[HLP];
    __shared__ float se[HLP];
    __shared__ float smax[N_HEADS];
    __shared__ float srsum[N_HEADS];

    const int nq  = blockIdx.x;           // n*LQ + q
    const int n   = nq >> 12;             // LQ = 4096
    const int tid = threadIdx.x;

    {
        const int l = (tid >> 2) & 3;     // tid = m*16 + l*4 + p
        const float off   = P[(size_t)nq * 256 + tid];
        const float logit = P[(size_t)nq * 256 + 128 + tid];
        const float T     = (float)shapes[l];
        const float ref   = refp[(size_t)nq * N_LEVELS + l];
        float x = ref * T + off - 0.5f;
        x = fminf(fmaxf(x, 0.0f), T - 1.0f);
        const float x0 = floorf(x);
        const int   i0 = (int)x0;
        const int   i1 = min(i0 + 1, shapes[l] - 1);
        const int   base = lstart[l];
        sg0[tid] = i0 + base;
        sg1[tid] = i1 + base;
        sw[tid]  = x - x0;
        se[tid]  = logit;
    }
    __syncthreads();
    if (tid < N_HEADS) {
        float mx = -1e30f;
        #pragma unroll
        for (int i = 0; i < 16; ++i) mx = fmaxf(mx, se[tid * 16 + i]);
        smax[tid] = mx;
    }
    __syncthreads();
    se[tid] = __expf(se[tid] - smax[tid >> 4]);
    __syncthreads();
    if (tid < N_HEADS) {
        float s = 0.f;
        #pragma unroll
        for (int i = 0; i < 16; ++i) s += se[tid * 16 + i];
        srsum[tid] = 1.0f / s;
    }
    __syncthreads();

    const int m  = tid >> 4;              // head
    const int dp = tid & 15;              // dim pair
    const float rs = srsum[m];
    // value element: ((n*S + s)*8 + m)*32 + 2*dp
    const unsigned short* vbase = value + (size_t)n * S_LEN * 256 + m * 32 + 2 * dp;

    float acc0 = 0.f, acc1 = 0.f;
    #pragma unroll
    for (int i = 0; i < 16; ++i) {
        const int j = m * 16 + i;
        const float a = se[j] * rs;
        const float ww = sw[j];
        const unsigned int u0 = *(const unsigned int*)(vbase + (size_t)sg0[j] * 256);
        const unsigned int u1 = *(const unsigned int*)(vbase + (size_t)sg1[j] * 256);
        const float v0a = bf2f((unsigned short)(u0 & 0xffff));
        const float v0b = bf2f((unsigned short)(u0 >> 16));
        const float v1a = bf2f((unsigned short)(u1 & 0xffff));
        const float v1b = bf2f((unsigned short)(u1 >> 16));
        acc0 += a * (v0a + ww * (v1a - v0a));
        acc1 += a * (v0b + ww * (v1b - v0b));
    }
    unsigned int out = (unsigned int)f2bf(acc0) | ((unsigned int)f2bf(acc1) << 16);
    *(unsigned int*)(tout + (size_t)nq * 256 + 2 * tid) = out;
}

// ---------------------------------------------------------------------------
extern "C" void kernel_launch(void* const* d_in, const int* in_sizes, int n_in,
                              void* d_out, int out_size, void* d_ws, size_t ws_size,
                              hipStream_t stream)
{
    const float* query  = (const float*)d_in[0];
    const float* refp   = (const float*)d_in[1];
    const float* inflat = (const float*)d_in[2];
    const int*   shapes = (const int*)d_in[3];
    const int*   lstart = (const int*)d_in[4];
    const float* W_off  = (const float*)d_in[5];
    const float* b_off  = (const float*)d_in[6];
    const float* W_aw   = (const float*)d_in[7];
    const float* b_aw   = (const float*)d_in[8];
    const float* W_v    = (const float*)d_in[9];
    const float* b_v    = (const float*)d_in[10];
    const float* W_out  = (const float*)d_in[11];
    const float* b_out  = (const float*)d_in[12];

    const int M_val = NBATCH * S_LEN;    // 30720
    const int M_q   = NBATCH * LQ;       // 16384
    const int n_val = M_val * D_MODEL;   // 7,864,320
    const int n_q   = M_q * D_MODEL;     // 4,194,304

    // ---- workspace layout ----
    char* p = (char*)d_ws;
    unsigned short* value_bf  = (unsigned short*)p; p += (size_t)n_val * 2;   // 15.7 MB
    float*          P         = (float*)p;          p += (size_t)M_q * 256 * 4; // 16.8 MB
    unsigned short* inflat_bf = (unsigned short*)p; p += (size_t)n_val * 2;   // 15.7 MB
    unsigned short* query_bf  = (unsigned short*)p; p += (size_t)n_q * 2;     // 8.4 MB
    unsigned short* tbuf      = query_bf;  // alias: query_bf dead after P-GEMM
    unsigned short* Wv_t      = (unsigned short*)p; p += 256 * 256 * 2;
    unsigned short* Wcat_t    = (unsigned short*)p; p += 256 * 256 * 2;
    unsigned short* Wout_t    = (unsigned short*)p; p += 256 * 256 * 2;
    float*          bcat      = (float*)p;          p += 256 * 4;

    // ---- conversions / weight prep ----
    conv_bf16_kernel<<<(n_val / 8 + 255) / 256, 256, 0, stream>>>(inflat, inflat_bf, n_val);
    conv_bf16_kernel<<<(n_q / 8 + 255) / 256, 256, 0, stream>>>(query, query_bf, n_q);
    transpose_w_kernel<<<dim3(4, 4), 256, 0, stream>>>(W_v, Wv_t, 256);
    transpose_w_kernel<<<dim3(2, 4), 256, 0, stream>>>(W_off, Wcat_t, 128);
    transpose_w_kernel<<<dim3(2, 4), 256, 0, stream>>>(W_aw, Wcat_t + 128 * 256, 128);
    transpose_w_kernel<<<dim3(4, 4), 256, 0, stream>>>(W_out, Wout_t, 256);
    bias_cat_kernel<<<1, 256, 0, stream>>>(b_off, b_aw, bcat);

    // ---- GEMMs + sampling ----
    // value = input_flatten @ W_v + b_v   (bf16 out)
    mfma_gemm_kernel<true><<<dim3(2, M_val / 128), 256, 0, stream>>>(
        inflat_bf, Wv_t, b_v, value_bf, M_val);
    // P = query @ [W_off | W_aw] + bcat   (fp32 out)
    mfma_gemm_kernel<false><<<dim3(2, M_q / 128), 256, 0, stream>>>(
        query_bf, Wcat_t, bcat, P, M_q);
    // sampling + softmax -> tbuf (bf16)
    sample_kernel<<<M_q, 128, 0, stream>>>(P, refp, shapes, lstart, value_bf, tbuf);
    // out = tbuf @ W_out + b_out          (fp32 out)
    mfma_gemm_kernel<false><<<dim3(2, M_q / 128), 256, 0, stream>>>(
        tbuf, Wout_t, b_out, (float*)d_out, M_q);
}

// Round 3
// 173.657 us; speedup vs baseline: 1.6523x; 1.0370x over previous
//
#include <hip/hip_runtime.h>
#include <hip/hip_bf16.h>
#include <cstddef>
#include <cstdint>

#define D_MODEL   256
#define N_HEADS   8
#define N_LEVELS  4
#define N_POINTS  4
#define D_HEAD    32
#define HLP       128      // N_HEADS*N_LEVELS*N_POINTS
#define NBATCH    4
#define LQ        4096
#define S_LEN     7680     // 4096+2048+1024+512

typedef __attribute__((ext_vector_type(8))) short  short8;
typedef __attribute__((ext_vector_type(4))) float  f32x4;
typedef __attribute__((ext_vector_type(8))) unsigned short ushort8;

__device__ __forceinline__ unsigned short f2bf(float x) {
    __hip_bfloat16 h = __float2bfloat16(x);
    return *reinterpret_cast<unsigned short*>(&h);
}
__device__ __forceinline__ float bf2f(unsigned short u) {
    unsigned int v = ((unsigned int)u) << 16;
    return *reinterpret_cast<float*>(&v);
}

__device__ __forceinline__ void gload_lds16(const void* g, void* l) {
    __builtin_amdgcn_global_load_lds(
        (const __attribute__((address_space(1))) void*)g,
        (__attribute__((address_space(3))) void*)l,
        16, 0, 0);
}

// ---------------------------------------------------------------------------
// Fused weight prep: transpose [K=256][N] fp32 -> [N][K=256] bf16 for
// W_v (z=0), [W_off|W_aw] concat (z=1), W_out (z=2). Block (0,0,1) also
// writes bcat = [b_off|b_aw]. Grid (4,4,3), 256 threads.
// ---------------------------------------------------------------------------
__global__ __launch_bounds__(256) void prep_kernel(
    const float* __restrict__ W_v,  const float* __restrict__ W_off,
    const float* __restrict__ W_aw, const float* __restrict__ W_out,
    const float* __restrict__ b_off, const float* __restrict__ b_aw,
    unsigned short* __restrict__ Wv_t, unsigned short* __restrict__ Wcat_t,
    unsigned short* __restrict__ Wout_t, float* __restrict__ bcat)
{
    __shared__ float t[64][65];
    const int z   = blockIdx.z;
    const int k0  = blockIdx.y * 64;
    const int n0  = blockIdx.x * 64;     // dst col block
    const int tid = threadIdx.x;

    const float* src; int srcN; int cs; unsigned short* dst;
    if (z == 0)      { src = W_v;   srcN = 256; cs = n0;       dst = Wv_t;  }
    else if (z == 2) { src = W_out; srcN = 256; cs = n0;       dst = Wout_t;}
    else if (n0 < 128){ src = W_off; srcN = 128; cs = n0;      dst = Wcat_t;}
    else             { src = W_aw;  srcN = 128; cs = n0 - 128; dst = Wcat_t;}

    #pragma unroll
    for (int i = 0; i < 16; ++i) {
        int idx = tid + i * 256;
        int kk = idx >> 6, nn = idx & 63;
        t[kk][nn] = src[(size_t)(k0 + kk) * srcN + cs + nn];
    }
    __syncthreads();
    #pragma unroll
    for (int i = 0; i < 16; ++i) {
        int idx = tid + i * 256;
        int nn = idx >> 6, kk = idx & 63;
        dst[(size_t)(n0 + nn) * 256 + k0 + kk] = f2bf(t[kk][nn]);
    }
    if (z == 1 && blockIdx.x == 0 && blockIdx.y == 0) {
        bcat[tid] = (tid < 128) ? b_off[tid] : b_aw[tid - 128];
    }
}

// ---------------------------------------------------------------------------
// bf16 MFMA GEMM: C[M,256] = A[M,256] @ Bt[256,256]^T + bias.
// A_FP32: A is row-major fp32, converted to bf16 during LDS staging.
// else:   A is row-major bf16, staged via global_load_lds width 16.
// Bt is N-major bf16 [256 n][256 k] (always global_load_lds).
// 128x128 tile, 256 threads = 4 waves (2x2), 16x16x32 MFMA, BK=32.
// ---------------------------------------------------------------------------
template <bool A_FP32, bool BF16_OUT>
__global__ __launch_bounds__(256) void mfma_gemm_kernel(
    const void* __restrict__ Aptr,
    const unsigned short* __restrict__ Bt,
    const float* __restrict__ bias,
    void* __restrict__ Cout, int M)
{
    __shared__ alignas(16) unsigned short Als[8][64][8];   // 8 KiB
    __shared__ alignas(16) unsigned short Bls[8][64][8];   // 8 KiB

    const int tid  = threadIdx.x;
    const int lane = tid & 63;
    const int w    = tid >> 6;        // wave 0..3
    const int wm   = w & 1;           // row half
    const int wn   = w >> 1;          // col half
    const int row0 = blockIdx.y * 128;
    const int col0 = blockIdx.x * 128;

    const int lr = (lane & 15);       // fragment row (A) / n (B)
    const int lk = (lane >> 4) * 8;   // fragment k offset

    f32x4 acc[4][4] = {};

    for (int kt = 0; kt < 8; ++kt) {
        const int k0 = kt * 32;
        #pragma unroll
        for (int c = 0; c < 2; ++c) {
            const int im = w * 2 + c;
            if (A_FP32) {
                const float* Af = (const float*)Aptr;
                const float* ap = Af + (size_t)(row0 + im * 16 + lr) * 256 + k0 + lk;
                const float4 a0 = *(const float4*)(ap);
                const float4 a1 = *(const float4*)(ap + 4);
                short8 pk;
                pk[0] = (short)f2bf(a0.x); pk[1] = (short)f2bf(a0.y);
                pk[2] = (short)f2bf(a0.z); pk[3] = (short)f2bf(a0.w);
                pk[4] = (short)f2bf(a1.x); pk[5] = (short)f2bf(a1.y);
                pk[6] = (short)f2bf(a1.z); pk[7] = (short)f2bf(a1.w);
                *(short8*)&Als[im][lane][0] = pk;
            } else {
                const unsigned short* Ab = (const unsigned short*)Aptr;
                const size_t ga = (size_t)(row0 + im * 16 + lr) * 256 + k0 + lk;
                gload_lds16(Ab + ga, &Als[im][0][0]);
            }
            const size_t gb = (size_t)(col0 + im * 16 + lr) * 256 + k0 + lk;
            gload_lds16(Bt + gb, &Bls[im][0][0]);
        }
        __syncthreads();

        short8 af[4], bfr[4];
        #pragma unroll
        for (int i = 0; i < 4; ++i) af[i]  = *(const short8*)&Als[wm * 4 + i][lane][0];
        #pragma unroll
        for (int j = 0; j < 4; ++j) bfr[j] = *(const short8*)&Bls[wn * 4 + j][lane][0];

        #pragma unroll
        for (int i = 0; i < 4; ++i)
            #pragma unroll
            for (int j = 0; j < 4; ++j)
                acc[i][j] = __builtin_amdgcn_mfma_f32_16x16x32_bf16(
                    af[i], bfr[j], acc[i][j], 0, 0, 0);
        __syncthreads();
    }

    // epilogue: C/D layout col=lane&15, row=(lane>>4)*4+reg
    const int r0 = row0 + wm * 64;
    const int c0 = col0 + wn * 64;
    const int prow = (lane >> 4) * 4;
    const int pcol = lane & 15;
    #pragma unroll
    for (int j = 0; j < 4; ++j) {
        const int col = c0 + j * 16 + pcol;
        const float bs = bias[col];
        #pragma unroll
        for (int i = 0; i < 4; ++i) {
            #pragma unroll
            for (int r = 0; r < 4; ++r) {
                const int row = r0 + i * 16 + prow + r;
                const float v = acc[i][j][r] + bs;
                if (BF16_OUT)
                    ((unsigned short*)Cout)[(size_t)row * 256 + col] = f2bf(v);
                else
                    ((float*)Cout)[(size_t)row * 256 + col] = v;
            }
        }
    }
}

// ---------------------------------------------------------------------------
// Sampling + softmax. 8 queries per block, 256 threads.
// XCD swizzle: 2 XCDs per batch n -> each XCD's L2 holds one 3.93 MB slice.
// Gather phase: 32 lanes per query = 8 heads x 4 lanes, 16 B dwordx4 each.
// ---------------------------------------------------------------------------
__global__ __launch_bounds__(256) void sample_kernel(
    const float* __restrict__ P, const float* __restrict__ refp,
    const int* __restrict__ shapes, const int* __restrict__ lstart,
    const unsigned short* __restrict__ value, unsigned short* __restrict__ tout)
{
    __shared__ int   sG0[8][HLP];
    __shared__ int   sG1[8][HLP];
    __shared__ float sW [8][HLP];
    __shared__ float sA [8][HLP];

    const int b    = blockIdx.x;       // 0..2047
    const int xcd  = b & 7;
    const int slot = b >> 3;           // 0..255
    const int n    = xcd >> 1;         // batch: 2 XCDs per batch slice
    const int qg   = (slot << 1) | (xcd & 1);   // 0..511
    const int nq0  = n * LQ + qg * 8;
    const int tid  = threadIdx.x;

    // phase 1: locations + logits for 8 queries x 128 (m,l,p)
    #pragma unroll
    for (int i = 0; i < 4; ++i) {
        const int idx = tid + i * 256;
        const int q   = idx >> 7;
        const int j   = idx & 127;
        const int l   = (j >> 2) & 3;
        const int nq  = nq0 + q;
        const float off   = P[(size_t)nq * 256 + j];
        const float logit = P[(size_t)nq * 256 + 128 + j];
        const float T     = (float)shapes[l];
        const float ref   = refp[(size_t)nq * N_LEVELS + l];
        float x = ref * T + off - 0.5f;
        x = fminf(fmaxf(x, 0.0f), T - 1.0f);
        const float x0 = floorf(x);
        const int   i0 = (int)x0;
        const int   i1 = min(i0 + 1, shapes[l] - 1);
        const int   base = lstart[l];
        sG0[q][j] = i0 + base;
        sG1[q][j] = i1 + base;
        sW [q][j] = x - x0;
        sA [q][j] = logit;
    }
    __syncthreads();

    // phase 2: softmax over 16 logits for each of 64 (q, head) pairs
    if (tid < 64) {
        const int q = tid >> 3;
        const int m = tid & 7;
        float e[16];
        float mx = -1e30f;
        #pragma unroll
        for (int i = 0; i < 16; ++i) { e[i] = sA[q][m * 16 + i]; mx = fmaxf(mx, e[i]); }
        float s = 0.f;
        #pragma unroll
        for (int i = 0; i < 16; ++i) { e[i] = __expf(e[i] - mx); s += e[i]; }
        const float rs = 1.0f / s;
        #pragma unroll
        for (int i = 0; i < 16; ++i) sA[q][m * 16 + i] = e[i] * rs;
    }
    __syncthreads();

    // phase 3: gather + interpolate + weight. 32 lanes/query.
    const int q  = tid >> 5;
    const int r  = tid & 31;
    const int m  = r >> 2;            // head
    const int ql = r & 3;             // 8-dim group
    const unsigned short* vb = value + (size_t)n * S_LEN * 256 + m * 32 + ql * 8;

    float acc[8] = {};
    #pragma unroll
    for (int i = 0; i < 16; ++i) {
        const int j = m * 16 + i;
        const float a  = sA[q][j];
        const float ww = sW[q][j];
        const ushort8 u0 = *(const ushort8*)(vb + (size_t)sG0[q][j] * 256);
        const ushort8 u1 = *(const ushort8*)(vb + (size_t)sG1[q][j] * 256);
        #pragma unroll
        for (int d = 0; d < 8; ++d) {
            const float v0 = bf2f(u0[d]);
            const float v1 = bf2f(u1[d]);
            acc[d] += a * (v0 + ww * (v1 - v0));
        }
    }
    ushort8 o;
    #pragma unroll
    for (int d = 0; d < 8; ++d) o[d] = f2bf(acc[d]);
    *(ushort8*)(tout + (size_t)(nq0 + q) * 256 + r * 8) = o;
}

// ---------------------------------------------------------------------------
extern "C" void kernel_launch(void* const* d_in, const int* in_sizes, int n_in,
                              void* d_out, int out_size, void* d_ws, size_t ws_size,
                              hipStream_t stream)
{
    const float* query  = (const float*)d_in[0];
    const float* refp   = (const float*)d_in[1];
    const float* inflat = (const float*)d_in[2];
    const int*   shapes = (const int*)d_in[3];
    const int*   lstart = (const int*)d_in[4];
    const float* W_off  = (const float*)d_in[5];
    const float* b_off  = (const float*)d_in[6];
    const float* W_aw   = (const float*)d_in[7];
    const float* b_aw   = (const float*)d_in[8];
    const float* W_v    = (const float*)d_in[9];
    const float* b_v    = (const float*)d_in[10];
    const float* W_out  = (const float*)d_in[11];
    const float* b_out  = (const float*)d_in[12];

    const int M_val = NBATCH * S_LEN;    // 30720
    const int M_q   = NBATCH * LQ;       // 16384

    // ---- workspace layout ----
    char* p = (char*)d_ws;
    unsigned short* value_bf = (unsigned short*)p; p += (size_t)M_val * D_MODEL * 2; // 15.7 MB
    float*          P        = (float*)p;          p += (size_t)M_q * 256 * 4;       // 16.8 MB
    unsigned short* tbuf     = (unsigned short*)p; p += (size_t)M_q * D_MODEL * 2;   // 8.4 MB
    unsigned short* Wv_t     = (unsigned short*)p; p += 256 * 256 * 2;
    unsigned short* Wcat_t   = (unsigned short*)p; p += 256 * 256 * 2;
    unsigned short* Wout_t   = (unsigned short*)p; p += 256 * 256 * 2;
    float*          bcat     = (float*)p;          p += 256 * 4;

    // 1. weight prep (one kernel)
    prep_kernel<<<dim3(4, 4, 3), 256, 0, stream>>>(
        W_v, W_off, W_aw, W_out, b_off, b_aw, Wv_t, Wcat_t, Wout_t, bcat);
    // 2. value = input_flatten @ W_v + b_v    (fp32 A fused-convert, bf16 out)
    mfma_gemm_kernel<true, true><<<dim3(2, M_val / 128), 256, 0, stream>>>(
        inflat, Wv_t, b_v, value_bf, M_val);
    // 3. P = query @ [W_off | W_aw] + bcat    (fp32 A fused-convert, fp32 out)
    mfma_gemm_kernel<true, false><<<dim3(2, M_q / 128), 256, 0, stream>>>(
        query, Wcat_t, bcat, P, M_q);
    // 4. sampling + softmax -> tbuf (bf16)
    sample_kernel<<<M_q / 8, 256, 0, stream>>>(
        P, refp, shapes, lstart, value_bf, tbuf);
    // 5. out = tbuf @ W_out + b_out           (bf16 A via lds-DMA, fp32 out)
    mfma_gemm_kernel<false, false><<<dim3(2, M_q / 128), 256, 0, stream>>>(
        tbuf, Wout_t, b_out, (float*)d_out, M_q);
}

// Round 4
// 162.160 us; speedup vs baseline: 1.7695x; 1.0709x over previous
//
#include <hip/hip_runtime.h>
#include <hip/hip_bf16.h>
#include <cstddef>
#include <cstdint>

#define D_MODEL   256
#define N_HEADS   8
#define N_LEVELS  4
#define N_POINTS  4
#define D_HEAD    32
#define HLP       128      // N_HEADS*N_LEVELS*N_POINTS
#define NBATCH    4
#define LQ        4096
#define S_LEN     7680     // 4096+2048+1024+512

typedef __attribute__((ext_vector_type(8))) short  short8;
typedef __attribute__((ext_vector_type(4))) float  f32x4;
typedef __attribute__((ext_vector_type(8))) unsigned short ushort8;

__device__ __forceinline__ unsigned short f2bf(float x) {
    __hip_bfloat16 h = __float2bfloat16(x);
    return *reinterpret_cast<unsigned short*>(&h);
}
__device__ __forceinline__ float bf2f(unsigned short u) {
    unsigned int v = ((unsigned int)u) << 16;
    return *reinterpret_cast<float*>(&v);
}

__device__ __forceinline__ void gload_lds16(const void* g, void* l) {
    __builtin_amdgcn_global_load_lds(
        (const __attribute__((address_space(1))) void*)g,
        (__attribute__((address_space(3))) void*)l,
        16, 0, 0);
}

// ---------------------------------------------------------------------------
// Fused weight prep: transpose [K=256][N] fp32 -> [N][K=256] bf16 for
// W_v (z=0), [W_off|W_aw] concat (z=1), W_out (z=2). Block (0,0,1) also
// writes bcat = [b_off|b_aw]. Grid (4,4,3), 256 threads.
// ---------------------------------------------------------------------------
__global__ __launch_bounds__(256) void prep_kernel(
    const float* __restrict__ W_v,  const float* __restrict__ W_off,
    const float* __restrict__ W_aw, const float* __restrict__ W_out,
    const float* __restrict__ b_off, const float* __restrict__ b_aw,
    unsigned short* __restrict__ Wv_t, unsigned short* __restrict__ Wcat_t,
    unsigned short* __restrict__ Wout_t, float* __restrict__ bcat)
{
    __shared__ float t[64][65];
    const int z   = blockIdx.z;
    const int k0  = blockIdx.y * 64;
    const int n0  = blockIdx.x * 64;     // dst col block
    const int tid = threadIdx.x;

    const float* src; int srcN; int cs; unsigned short* dst;
    if (z == 0)      { src = W_v;   srcN = 256; cs = n0;       dst = Wv_t;  }
    else if (z == 2) { src = W_out; srcN = 256; cs = n0;       dst = Wout_t;}
    else if (n0 < 128){ src = W_off; srcN = 128; cs = n0;      dst = Wcat_t;}
    else             { src = W_aw;  srcN = 128; cs = n0 - 128; dst = Wcat_t;}

    #pragma unroll
    for (int i = 0; i < 16; ++i) {
        int idx = tid + i * 256;
        int kk = idx >> 6, nn = idx & 63;
        t[kk][nn] = src[(size_t)(k0 + kk) * srcN + cs + nn];
    }
    __syncthreads();
    #pragma unroll
    for (int i = 0; i < 16; ++i) {
        int idx = tid + i * 256;
        int nn = idx >> 6, kk = idx & 63;
        dst[(size_t)(n0 + nn) * 256 + k0 + kk] = f2bf(t[kk][nn]);
    }
    if (z == 1 && blockIdx.x == 0 && blockIdx.y == 0) {
        bcat[tid] = (tid < 128) ? b_off[tid] : b_aw[tid - 128];
    }
}

// ---------------------------------------------------------------------------
// Fused value-GEMM + P-GEMM. Grid 736 blocks, 256 thr (4 waves, 2x2).
// job < 480 : value tile -> value2 bf16, layout [n][g][s][128]
// job >= 480: P tile     -> P fp32 [nq][256]
// A fp32 row-major (converted while staging); Bt bf16 N-major [n][k].
// 128x128 tile, 16x16x32 MFMA, BK=32.
// ---------------------------------------------------------------------------
__global__ __launch_bounds__(256) void gemm_vp_kernel(
    const float* __restrict__ inflat, const float* __restrict__ query,
    const unsigned short* __restrict__ Wv_t, const unsigned short* __restrict__ Wcat_t,
    const float* __restrict__ b_v, const float* __restrict__ bcat,
    unsigned short* __restrict__ value2, float* __restrict__ P)
{
    __shared__ alignas(16) unsigned short Als[8][64][8];   // 8 KiB
    __shared__ alignas(16) unsigned short Bls[8][64][8];   // 8 KiB

    const int job = blockIdx.x;
    const bool is_val = (job < 480);
    const int jj   = is_val ? job : (job - 480);
    const int row0 = (jj >> 1) * 128;
    const int col0 = (jj & 1) * 128;
    const float* A = is_val ? inflat : query;
    const unsigned short* Bt = is_val ? Wv_t : Wcat_t;
    const float* bias = is_val ? b_v : bcat;

    const int tid  = threadIdx.x;
    const int lane = tid & 63;
    const int w    = tid >> 6;
    const int wm   = w & 1;
    const int wn   = w >> 1;
    const int lr   = lane & 15;
    const int lk   = (lane >> 4) * 8;

    f32x4 acc[4][4] = {};

    for (int kt = 0; kt < 8; ++kt) {
        const int k0 = kt * 32;
        #pragma unroll
        for (int c = 0; c < 2; ++c) {
            const int im = w * 2 + c;
            const float* ap = A + (size_t)(row0 + im * 16 + lr) * 256 + k0 + lk;
            const float4 a0 = *(const float4*)(ap);
            const float4 a1 = *(const float4*)(ap + 4);
            short8 pk;
            pk[0] = (short)f2bf(a0.x); pk[1] = (short)f2bf(a0.y);
            pk[2] = (short)f2bf(a0.z); pk[3] = (short)f2bf(a0.w);
            pk[4] = (short)f2bf(a1.x); pk[5] = (short)f2bf(a1.y);
            pk[6] = (short)f2bf(a1.z); pk[7] = (short)f2bf(a1.w);
            *(short8*)&Als[im][lane][0] = pk;
            const size_t gb = (size_t)(col0 + im * 16 + lr) * 256 + k0 + lk;
            gload_lds16(Bt + gb, &Bls[im][0][0]);
        }
        __syncthreads();

        short8 af[4], bfr[4];
        #pragma unroll
        for (int i = 0; i < 4; ++i) af[i]  = *(const short8*)&Als[wm * 4 + i][lane][0];
        #pragma unroll
        for (int j = 0; j < 4; ++j) bfr[j] = *(const short8*)&Bls[wn * 4 + j][lane][0];

        #pragma unroll
        for (int i = 0; i < 4; ++i)
            #pragma unroll
            for (int j = 0; j < 4; ++j)
                acc[i][j] = __builtin_amdgcn_mfma_f32_16x16x32_bf16(
                    af[i], bfr[j], acc[i][j], 0, 0, 0);
        __syncthreads();
    }

    // epilogue: C/D layout col=lane&15, row=(lane>>4)*4+reg
    const int prow = (lane >> 4) * 4;
    const int pcol = lane & 15;
    if (is_val) {
        // row = n*7680 + s ; 7680 = 60*128 so blocks never straddle n.
        const int n  = row0 / S_LEN;
        const int s0 = row0 - n * S_LEN;
        const int gg = col0 >> 7;
        unsigned short* dst = value2 + ((size_t)(n * 2 + gg) * S_LEN + s0) * 128;
        #pragma unroll
        for (int j = 0; j < 4; ++j) {
            const int inner = wn * 64 + j * 16 + pcol;   // 0..127
            const float bs = bias[col0 + inner];
            #pragma unroll
            for (int i = 0; i < 4; ++i) {
                #pragma unroll
                for (int r = 0; r < 4; ++r) {
                    const int rl = wm * 64 + i * 16 + prow + r;
                    dst[(size_t)rl * 128 + inner] = f2bf(acc[i][j][r] + bs);
                }
            }
        }
    } else {
        #pragma unroll
        for (int j = 0; j < 4; ++j) {
            const int col = col0 + wn * 64 + j * 16 + pcol;
            const float bs = bias[col];
            #pragma unroll
            for (int i = 0; i < 4; ++i) {
                #pragma unroll
                for (int r = 0; r < 4; ++r) {
                    const int row = row0 + wm * 64 + i * 16 + prow + r;
                    P[(size_t)row * 256 + col] = acc[i][j][r] + bs;
                }
            }
        }
    }
}

// ---------------------------------------------------------------------------
// bf16 MFMA GEMM for out-proj: C[M,256] = A[M,256] @ Bt^T + bias (fp32 out).
// A row-major bf16 via global_load_lds. Same tile structure as gemm_vp.
// ---------------------------------------------------------------------------
__global__ __launch_bounds__(256) void gemm_out_kernel(
    const unsigned short* __restrict__ A,
    const unsigned short* __restrict__ Bt,
    const float* __restrict__ bias,
    float* __restrict__ Cout)
{
    __shared__ alignas(16) unsigned short Als[8][64][8];
    __shared__ alignas(16) unsigned short Bls[8][64][8];

    const int tid  = threadIdx.x;
    const int lane = tid & 63;
    const int w    = tid >> 6;
    const int wm   = w & 1;
    const int wn   = w >> 1;
    const int row0 = blockIdx.y * 128;
    const int col0 = blockIdx.x * 128;
    const int lr   = lane & 15;
    const int lk   = (lane >> 4) * 8;

    f32x4 acc[4][4] = {};

    for (int kt = 0; kt < 8; ++kt) {
        const int k0 = kt * 32;
        #pragma unroll
        for (int c = 0; c < 2; ++c) {
            const int im = w * 2 + c;
            gload_lds16(A + (size_t)(row0 + im * 16 + lr) * 256 + k0 + lk, &Als[im][0][0]);
            gload_lds16(Bt + (size_t)(col0 + im * 16 + lr) * 256 + k0 + lk, &Bls[im][0][0]);
        }
        __syncthreads();

        short8 af[4], bfr[4];
        #pragma unroll
        for (int i = 0; i < 4; ++i) af[i]  = *(const short8*)&Als[wm * 4 + i][lane][0];
        #pragma unroll
        for (int j = 0; j < 4; ++j) bfr[j] = *(const short8*)&Bls[wn * 4 + j][lane][0];

        #pragma unroll
        for (int i = 0; i < 4; ++i)
            #pragma unroll
            for (int j = 0; j < 4; ++j)
                acc[i][j] = __builtin_amdgcn_mfma_f32_16x16x32_bf16(
                    af[i], bfr[j], acc[i][j], 0, 0, 0);
        __syncthreads();
    }

    const int prow = (lane >> 4) * 4;
    const int pcol = lane & 15;
    #pragma unroll
    for (int j = 0; j < 4; ++j) {
        const int col = col0 + wn * 64 + j * 16 + pcol;
        const float bs = bias[col];
        #pragma unroll
        for (int i = 0; i < 4; ++i) {
            #pragma unroll
            for (int r = 0; r < 4; ++r) {
                const int row = row0 + wm * 64 + i * 16 + prow + r;
                Cout[(size_t)row * 256 + col] = acc[i][j][r] + bs;
            }
        }
    }
}

// ---------------------------------------------------------------------------
// Sampling + softmax, XCD-partitioned. Grid 2048 blocks, 256 threads.
// blockIdx&7 selects (n, head-half g): the block gathers ONLY from
// value2[n][g] (1.97 MB) which stays resident in that XCD's 4 MB L2.
// P/refp reads are nontemporal so the stream cannot evict value2.
// Each block: 16 queries x 4 heads x 32 dims.
// ---------------------------------------------------------------------------
__global__ __launch_bounds__(256) void sample_kernel(
    const float* __restrict__ P, const float* __restrict__ refp,
    const int* __restrict__ shapes, const int* __restrict__ lstart,
    const unsigned short* __restrict__ value2, unsigned short* __restrict__ tout)
{
    __shared__ int   sG0[16][65];
    __shared__ int   sG1[16][65];
    __shared__ float sW [16][65];
    __shared__ float sA [16][65];

    const int b   = blockIdx.x;          // 0..2047
    const int xcd = b & 7;               // (n<<1) | g
    const int n   = xcd >> 1;
    const int g   = xcd & 1;             // head half (heads g*4 .. g*4+3)
    const int q0  = (b >> 3) * 16;
    const int nq0 = n * LQ + q0;
    const int tid = threadIdx.x;

    // phase 1: locations + logits for 16 queries x 64 (mh,l,p)
    #pragma unroll
    for (int it = 0; it < 4; ++it) {
        const int idx = tid + it * 256;   // 0..1023
        const int q   = idx >> 6;
        const int jl  = idx & 63;         // mh*16 + l*4 + p
        const int l   = (jl >> 2) & 3;
        const int jg  = g * 64 + jl;      // global point index 0..127
        const int nq  = nq0 + q;
        const float off   = __builtin_nontemporal_load(P + (size_t)nq * 256 + jg);
        const float logit = __builtin_nontemporal_load(P + (size_t)nq * 256 + 128 + jg);
        const float ref   = __builtin_nontemporal_load(refp + (size_t)nq * N_LEVELS + l);
        const int   sh    = shapes[l];
        const float T     = (float)sh;
        float x = ref * T + off - 0.5f;
        x = fminf(fmaxf(x, 0.0f), T - 1.0f);
        const float x0 = floorf(x);
        const int   i0 = (int)x0;
        const int   i1 = min(i0 + 1, sh - 1);
        const int   base = lstart[l];
        sG0[q][jl] = i0 + base;
        sG1[q][jl] = i1 + base;
        sW [q][jl] = x - x0;
        sA [q][jl] = logit;
    }
    __syncthreads();

    // phase 2: softmax over 16 points for each of 64 (q, mh) pairs
    if (tid < 64) {
        const int q  = tid >> 2;
        const int mh = tid & 3;
        float e[16];
        float mx = -1e30f;
        #pragma unroll
        for (int i = 0; i < 16; ++i) { e[i] = sA[q][mh * 16 + i]; mx = fmaxf(mx, e[i]); }
        float s = 0.f;
        #pragma unroll
        for (int i = 0; i < 16; ++i) { e[i] = __expf(e[i] - mx); s += e[i]; }
        const float rs = 1.0f / s;
        #pragma unroll
        for (int i = 0; i < 16; ++i) sA[q][mh * 16 + i] = e[i] * rs;
    }
    __syncthreads();

    // phase 3: gather + interpolate. 16 lanes/query (4 heads x 4 dim-groups).
    const int q  = tid >> 4;
    const int r  = tid & 15;
    const int mh = r >> 2;               // local head 0..3
    const int ql = r & 3;                // 8-dim group
    const unsigned short* vb =
        value2 + (size_t)xcd * S_LEN * 128 + mh * 32 + ql * 8;

    float acc[8] = {};
    #pragma unroll
    for (int i = 0; i < 16; ++i) {
        const int j = mh * 16 + i;
        const float a  = sA[q][j];
        const float ww = sW[q][j];
        const ushort8 u0 = *(const ushort8*)(vb + (size_t)sG0[q][j] * 128);
        const ushort8 u1 = *(const ushort8*)(vb + (size_t)sG1[q][j] * 128);
        #pragma unroll
        for (int d = 0; d < 8; ++d) {
            const float v0 = bf2f(u0[d]);
            const float v1 = bf2f(u1[d]);
            acc[d] += a * (v0 + ww * (v1 - v0));
        }
    }
    ushort8 o;
    #pragma unroll
    for (int d = 0; d < 8; ++d) o[d] = f2bf(acc[d]);
    __builtin_nontemporal_store(o,
        (ushort8*)(tout + (size_t)(nq0 + q) * 256 + g * 128 + mh * 32 + ql * 8));
}

// ---------------------------------------------------------------------------
extern "C" void kernel_launch(void* const* d_in, const int* in_sizes, int n_in,
                              void* d_out, int out_size, void* d_ws, size_t ws_size,
                              hipStream_t stream)
{
    const float* query  = (const float*)d_in[0];
    const float* refp   = (const float*)d_in[1];
    const float* inflat = (const float*)d_in[2];
    const int*   shapes = (const int*)d_in[3];
    const int*   lstart = (const int*)d_in[4];
    const float* W_off  = (const float*)d_in[5];
    const float* b_off  = (const float*)d_in[6];
    const float* W_aw   = (const float*)d_in[7];
    const float* b_aw   = (const float*)d_in[8];
    const float* W_v    = (const float*)d_in[9];
    const float* b_v    = (const float*)d_in[10];
    const float* W_out  = (const float*)d_in[11];
    const float* b_out  = (const float*)d_in[12];

    const int M_val = NBATCH * S_LEN;    // 30720
    const int M_q   = NBATCH * LQ;       // 16384

    // ---- workspace layout ----
    char* p = (char*)d_ws;
    unsigned short* value2 = (unsigned short*)p; p += (size_t)M_val * D_MODEL * 2; // 15.7 MB
    float*          P      = (float*)p;          p += (size_t)M_q * 256 * 4;       // 16.8 MB
    unsigned short* tbuf   = (unsigned short*)p; p += (size_t)M_q * D_MODEL * 2;   // 8.4 MB
    unsigned short* Wv_t   = (unsigned short*)p; p += 256 * 256 * 2;
    unsigned short* Wcat_t = (unsigned short*)p; p += 256 * 256 * 2;
    unsigned short* Wout_t = (unsigned short*)p; p += 256 * 256 * 2;
    float*          bcat   = (float*)p;          p += 256 * 4;

    // 1. weight prep
    prep_kernel<<<dim3(4, 4, 3), 256, 0, stream>>>(
        W_v, W_off, W_aw, W_out, b_off, b_aw, Wv_t, Wcat_t, Wout_t, bcat);
    // 2. value-GEMM (480 jobs) + P-GEMM (256 jobs), one dispatch
    gemm_vp_kernel<<<736, 256, 0, stream>>>(
        inflat, query, Wv_t, Wcat_t, b_v, bcat, value2, P);
    // 3. sampling + softmax -> tbuf (bf16), XCD-partitioned gathers
    sample_kernel<<<2048, 256, 0, stream>>>(
        P, refp, shapes, lstart, value2, tbuf);
    // 4. out = tbuf @ W_out + b_out
    gemm_out_kernel<<<dim3(2, M_q / 128), 256, 0, stream>>>(
        tbuf, Wout_t, b_out, (float*)d_out);
}